// Round 7
// baseline (248.140 us; speedup 1.0000x reference)
//
#include <hip/hip_runtime.h>
#include <stdint.h>

typedef __bf16 bf16x8 __attribute__((ext_vector_type(8)));
typedef float f32x4v __attribute__((ext_vector_type(4)));
typedef float f32x16v __attribute__((ext_vector_type(16)));
typedef unsigned u32x2 __attribute__((ext_vector_type(2)));

__device__ __forceinline__ unsigned f2bf_rn(float f) {
    return (__float_as_uint(f) + 0x8000u) >> 16;
}
__device__ __forceinline__ unsigned pk2bf(float a, float b) {
    return __builtin_amdgcn_perm(__float_as_uint(b) + 0x8000u,
                                 __float_as_uint(a) + 0x8000u, 0x07060302u);
}

__device__ __forceinline__ void swap32(unsigned &a, unsigned &b) {
#if __has_builtin(__builtin_amdgcn_permlane32_swap)
    u32x2 r = __builtin_amdgcn_permlane32_swap(a, b, false, false);
    a = r[0]; b = r[1];
#else
    unsigned pa = (unsigned)__shfl_xor((int)a, 32);
    unsigned pb = (unsigned)__shfl_xor((int)b, 32);
    bool hi = (threadIdx.x & 32) != 0;
    unsigned na = hi ? pb : a;
    unsigned nb = hi ? b : pa;
    a = na; b = nb;
#endif
}

__device__ __forceinline__ bf16x8 mk8(unsigned a, unsigned b, unsigned c, unsigned e) {
    union { int4 i; bf16x8 v; } u;
    u.i = make_int4((int)a, (int)b, (int)c, (int)e);
    return u.v;
}

#define GLD_LDS16(gp, lp) __builtin_amdgcn_global_load_lds( \
    (const __attribute__((address_space(1))) unsigned int*)(gp), \
    (__attribute__((address_space(3))) unsigned int*)(lp), 16, 0, 0)

// ---------------- prep: GroupNorm (blocks 0..511) + weight transpose (512..1535) ----
__global__ __launch_bounds__(256) void prep_kernel(const float* __restrict__ x,
        const float* __restrict__ scale, const float* __restrict__ bias,
        unsigned short* __restrict__ hnT,
        const float* __restrict__ wqkv, const float* __restrict__ wout,
        unsigned short* __restrict__ WqT, unsigned short* __restrict__ WoT) {
    __shared__ float red[256], red2[256];
    __shared__ float sc_s[16], bi_s[16];
    __shared__ float tile[16][260];
    __shared__ float wtile[32][33];
    int bid = blockIdx.x;
    int tid = threadIdx.x;
    if (bid >= 512) {                       // ---- weight transpose ----
        int b2 = bid - 512;
        int bx = b2 & 63, by = b2 >> 6;
        const float* in; unsigned short* out; int Cc, c0;
        if (bx < 48) { in = wqkv; out = WqT; Cc = 1536; c0 = bx * 32; }
        else         { in = wout; out = WoT; Cc = 512;  c0 = (bx - 48) * 32; }
        int r0 = by * 32;
        int tx = tid & 31, ty = tid >> 5;
        #pragma unroll
        for (int i = 0; i < 4; i++) {
            int r = ty + i * 8;
            wtile[r][tx] = in[(size_t)(r0 + r) * Cc + c0 + tx];
        }
        __syncthreads();
        #pragma unroll
        for (int i = 0; i < 4; i++) {
            int cr = ty + i * 8;
            out[(size_t)(c0 + cr) * 512 + r0 + tx] = (unsigned short)f2bf_rn(wtile[tx][cr]);
        }
        return;
    }
    // ---- GroupNorm ----
    int blk = bid;                          // n*32+g
    int g = blk & 31, n = blk >> 5;
    const float4* src4 = (const float4*)(x + (size_t)blk * 16384);

    float s = 0.f, s2 = 0.f;
    for (int i = tid; i < 4096; i += 256) {
        float4 v = src4[i];
        s  += v.x + v.y + v.z + v.w;
        s2 += v.x*v.x + v.y*v.y + v.z*v.z + v.w*v.w;
    }
    red[tid] = s; red2[tid] = s2;
    __syncthreads();
    for (int off = 128; off > 0; off >>= 1) {
        if (tid < off) { red[tid] += red[tid+off]; red2[tid] += red2[tid+off]; }
        __syncthreads();
    }
    if (tid < 16) {
        float mean = red[0] * (1.f/16384.f);
        float var  = red2[0] * (1.f/16384.f) - mean*mean;
        float rstd = rsqrtf(var + 1e-6f);
        int c = g*16 + tid;
        float sc = scale[c] * rstd;
        sc_s[tid] = sc;
        bi_s[tid] = bias[c] - mean * sc;
    }
    for (int ch = 0; ch < 4; ch++) {
        __syncthreads();
        #pragma unroll
        for (int kk = 0; kk < 4; kk++) {
            int fi = tid + kk*256;
            int row = fi >> 6, col4 = fi & 63;
            float4 v = src4[row*256 + ch*64 + col4];
            *(float4*)&tile[row][col4*4] = v;
        }
        __syncthreads();
        int sQ = ch*256 + tid;
        unsigned int pk[8];
        #pragma unroll
        for (int c2 = 0; c2 < 8; c2++) {
            float a = tile[c2*2][tid]   * sc_s[c2*2]   + bi_s[c2*2];
            float b = tile[c2*2+1][tid] * sc_s[c2*2+1] + bi_s[c2*2+1];
            pk[c2] = pk2bf(a, b);
        }
        unsigned short* op = hnT + ((size_t)(n*1024 + sQ))*512 + g*16;
        *(uint4*)op       = make_uint4(pk[0], pk[1], pk[2], pk[3]);
        *((uint4*)op + 1) = make_uint4(pk[4], pk[5], pk[6], pk[7]);
    }
}

// ---------------- QKV GEMM: D[m][s] = sum_c WqT[m][c]*hnT[s][c] ----------------
__global__ __launch_bounds__(256) void qkv_kernel(
        const unsigned short* __restrict__ WqT, const unsigned short* __restrict__ hnT,
        const float* __restrict__ bqkv,
        unsigned short* __restrict__ qb, unsigned short* __restrict__ kbuf,
        unsigned short* __restrict__ vb) {
    int s0 = blockIdx.x * 128, m0 = blockIdx.y * 128, n = blockIdx.z;
    __shared__ unsigned short At[4096];
    __shared__ unsigned short Bt[4096];
    int tid = threadIdx.x;
    int lane = tid & 63, w = tid >> 6;
    int quad = lane >> 4, tx = lane & 15;
    int moff = (w & 1) * 64, soff = (w >> 1) * 64;

    const unsigned short* Arow = WqT + (size_t)m0 * 512;
    const unsigned short* Brow = hnT + ((size_t)n * 1024 + s0) * 512;

    f32x4v acc[4][4];
    #pragma unroll
    for (int i = 0; i < 4; i++)
        #pragma unroll
        for (int j = 0; j < 4; j++)
            #pragma unroll
            for (int e = 0; e < 4; e++) acc[i][j][e] = 0.f;

    int f1 = tid, f2 = tid + 256;
    int m1 = f1 >> 2, kb1 = ((f1 & 3) - (f1 >> 3)) & 3;
    int m2 = f2 >> 2, kb2 = ((f2 & 3) - (f2 >> 3)) & 3;

    for (int k0 = 0; k0 < 512; k0 += 32) {
        __syncthreads();
        GLD_LDS16(Arow + (size_t)m1*512 + k0 + kb1*8, At + f1*8);
        GLD_LDS16(Arow + (size_t)m2*512 + k0 + kb2*8, At + f2*8);
        GLD_LDS16(Brow + (size_t)m1*512 + k0 + kb1*8, Bt + f1*8);
        GLD_LDS16(Brow + (size_t)m2*512 + k0 + kb2*8, Bt + f2*8);
        __syncthreads();
        bf16x8 af[4], bfr[4];
        #pragma unroll
        for (int mt = 0; mt < 4; mt++) {
            int m = moff + mt*16 + tx;
            int ch = m*4 + ((quad + (m >> 1)) & 3);
            af[mt] = *(const bf16x8*)(At + ch*8);
        }
        #pragma unroll
        for (int nt = 0; nt < 4; nt++) {
            int m = soff + nt*16 + tx;
            int ch = m*4 + ((quad + (m >> 1)) & 3);
            bfr[nt] = *(const bf16x8*)(Bt + ch*8);
        }
        #pragma unroll
        for (int mt = 0; mt < 4; mt++)
            #pragma unroll
            for (int nt = 0; nt < 4; nt++)
                acc[mt][nt] = __builtin_amdgcn_mfma_f32_16x16x32_bf16(
                    af[mt], bfr[nt], acc[mt][nt], 0, 0, 0);
    }

    const float QSCL = 0.18033688011112042f;   // 0.125*log2(e)
    #pragma unroll
    for (int mt = 0; mt < 4; mt++) {
        int m = m0 + moff + mt*16 + quad*4;
        int head = m / 192;
        int r = m - head*192;
        int which = r >> 6;
        int d0 = r & 63;
        float4 bia = *(const float4*)(bqkv + m);
        float scl = (which == 0) ? QSCL : 1.0f;
        #pragma unroll
        for (int nt = 0; nt < 4; nt++) {
            int sQ = s0 + soff + nt*16 + tx;
            f32x4v a = acc[mt][nt];
            float v0 = (a[0]+bia.x)*scl, v1 = (a[1]+bia.y)*scl;
            float v2 = (a[2]+bia.z)*scl, v3 = (a[3]+bia.w)*scl;
            if (which < 2) {
                unsigned short* base = (which == 0) ? qb : kbuf;
                unsigned lo = pk2bf(v0, v1), hi2 = pk2bf(v2, v3);
                *(uint2*)(base + (((size_t)(n*8 + head)*1024 + sQ) << 6) + d0) =
                    make_uint2(lo, hi2);
            } else {
                size_t vbase = ((size_t)(n*8 + head)*64 + d0)*1024 + sQ;
                vb[vbase]        = (unsigned short)f2bf_rn(v0);
                vb[vbase + 1024] = (unsigned short)f2bf_rn(v1);
                vb[vbase + 2048] = (unsigned short)f2bf_rn(v2);
                vb[vbase + 3072] = (unsigned short)f2bf_rn(v3);
            }
        }
    }
}

// ---------------- flash attention: 64 q per wave (2 independent subtiles) --------
// Fixed-max exp2 softmax; in-register P transpose via permlane32_swap.
__global__ __launch_bounds__(256) void attn_kernel(
        const unsigned short* __restrict__ qg, const unsigned short* __restrict__ kg,
        const unsigned short* __restrict__ vg, unsigned short* __restrict__ ao) {
    int bid = blockIdx.x;
    int nh = bid & 127, qbk = bid >> 7;     // 4 q-blocks of one head share an XCD
    int tid = threadIdx.x, w = tid >> 6, lane = tid & 63;
    int lq = lane & 31, hi = lane >> 5;
    const unsigned short* Q = qg + (size_t)nh * 65536;
    const unsigned short* K = kg + (size_t)nh * 65536;
    const unsigned short* V = vg + (size_t)nh * 65536;   // [d][t]

    __shared__ unsigned short Klds[2][64*72];            // [t][d], pad 8
    __shared__ unsigned short Vlds[2][64*72];            // [d][t], pad 8
    __shared__ float lsum_s[4][64];

    int q0 = qbk*256 + w*64;
    bf16x8 qfA[4], qfB[4];
    #pragma unroll
    for (int ks = 0; ks < 4; ks++) {
        qfA[ks] = *(const bf16x8*)(Q + ((size_t)(q0 + lq))*64      + ks*16 + hi*8);
        qfB[ks] = *(const bf16x8*)(Q + ((size_t)(q0 + 32 + lq))*64 + ks*16 + hi*8);
    }

    int r = tid >> 2, part = (tid & 3) * 16;
    uint4 ka, kb2, va, vb2;
    ka  = *(const uint4*)(K + (size_t)r*64 + part);
    kb2 = *(const uint4*)(K + (size_t)r*64 + part + 8);
    va  = *(const uint4*)(V + (size_t)r*1024 + part);
    vb2 = *(const uint4*)(V + (size_t)r*1024 + part + 8);

    f32x16v OA0, OA1, OB0, OB1;
    #pragma unroll
    for (int i = 0; i < 16; i++) { OA0[i]=0.f; OA1[i]=0.f; OB0[i]=0.f; OB1[i]=0.f; }
    float lsumA = 0.f, lsumB = 0.f;

    for (int it = 0; it < 16; it++) {
        int buf = it & 1;
        {
            unsigned short* kd = Klds[buf] + r*72 + part;
            *(uint4*)kd = ka; *(uint4*)(kd+8) = kb2;
            unsigned short* vd = Vlds[buf] + r*72 + part;
            *(uint4*)vd = va; *(uint4*)(vd+8) = vb2;
        }
        __syncthreads();
        if (it < 15) {
            int t0 = (it + 1) * 64;
            ka  = *(const uint4*)(K + (size_t)(t0 + r)*64 + part);
            kb2 = *(const uint4*)(K + (size_t)(t0 + r)*64 + part + 8);
            va  = *(const uint4*)(V + (size_t)r*1024 + t0 + part);
            vb2 = *(const uint4*)(V + (size_t)r*1024 + t0 + part + 8);
        }
        const unsigned short* Kb = Klds[buf];
        const unsigned short* Vb = Vlds[buf];

        // ---- subtile A ----
        {
            f32x16v S0, S1;
            #pragma unroll
            for (int i = 0; i < 16; i++) { S0[i] = 0.f; S1[i] = 0.f; }
            #pragma unroll
            for (int ks = 0; ks < 4; ks++) {
                bf16x8 a0 = *(const bf16x8*)(Kb + lq*72 + ks*16 + hi*8);
                bf16x8 a1 = *(const bf16x8*)(Kb + (32+lq)*72 + ks*16 + hi*8);
                S0 = __builtin_amdgcn_mfma_f32_32x32x16_bf16(a0, qfA[ks], S0, 0, 0, 0);
                S1 = __builtin_amdgcn_mfma_f32_32x32x16_bf16(a1, qfA[ks], S1, 0, 0, 0);
            }
            #pragma unroll
            for (int i = 0; i < 16; i++) {
                S0[i] = exp2f(S0[i]);
                S1[i] = exp2f(S1[i]);
                lsumA += S0[i] + S1[i];
            }
            unsigned d[16];
            #pragma unroll
            for (int p2 = 0; p2 < 8; p2++) {
                d[p2]     = pk2bf(S0[p2*2], S0[p2*2+1]);
                d[8 + p2] = pk2bf(S1[p2*2], S1[p2*2+1]);
            }
            swap32(d[0],  d[2]);  swap32(d[1],  d[3]);
            swap32(d[4],  d[6]);  swap32(d[5],  d[7]);
            swap32(d[8],  d[10]); swap32(d[9],  d[11]);
            swap32(d[12], d[14]); swap32(d[13], d[15]);
            #pragma unroll
            for (int kc = 0; kc < 4; kc++) {
                bf16x8 pa = mk8(d[kc*4+0], d[kc*4+1], d[kc*4+2], d[kc*4+3]);
                bf16x8 v0 = *(const bf16x8*)(Vb + lq*72 + kc*16 + hi*8);
                bf16x8 v1 = *(const bf16x8*)(Vb + (32+lq)*72 + kc*16 + hi*8);
                OA0 = __builtin_amdgcn_mfma_f32_32x32x16_bf16(pa, v0, OA0, 0, 0, 0);
                OA1 = __builtin_amdgcn_mfma_f32_32x32x16_bf16(pa, v1, OA1, 0, 0, 0);
            }
        }
        // ---- subtile B (independent chain; compiler interleaves with A) ----
        {
            f32x16v S0, S1;
            #pragma unroll
            for (int i = 0; i < 16; i++) { S0[i] = 0.f; S1[i] = 0.f; }
            #pragma unroll
            for (int ks = 0; ks < 4; ks++) {
                bf16x8 a0 = *(const bf16x8*)(Kb + lq*72 + ks*16 + hi*8);
                bf16x8 a1 = *(const bf16x8*)(Kb + (32+lq)*72 + ks*16 + hi*8);
                S0 = __builtin_amdgcn_mfma_f32_32x32x16_bf16(a0, qfB[ks], S0, 0, 0, 0);
                S1 = __builtin_amdgcn_mfma_f32_32x32x16_bf16(a1, qfB[ks], S1, 0, 0, 0);
            }
            #pragma unroll
            for (int i = 0; i < 16; i++) {
                S0[i] = exp2f(S0[i]);
                S1[i] = exp2f(S1[i]);
                lsumB += S0[i] + S1[i];
            }
            unsigned d[16];
            #pragma unroll
            for (int p2 = 0; p2 < 8; p2++) {
                d[p2]     = pk2bf(S0[p2*2], S0[p2*2+1]);
                d[8 + p2] = pk2bf(S1[p2*2], S1[p2*2+1]);
            }
            swap32(d[0],  d[2]);  swap32(d[1],  d[3]);
            swap32(d[4],  d[6]);  swap32(d[5],  d[7]);
            swap32(d[8],  d[10]); swap32(d[9],  d[11]);
            swap32(d[12], d[14]); swap32(d[13], d[15]);
            #pragma unroll
            for (int kc = 0; kc < 4; kc++) {
                bf16x8 pa = mk8(d[kc*4+0], d[kc*4+1], d[kc*4+2], d[kc*4+3]);
                bf16x8 v0 = *(const bf16x8*)(Vb + lq*72 + kc*16 + hi*8);
                bf16x8 v1 = *(const bf16x8*)(Vb + (32+lq)*72 + kc*16 + hi*8);
                OB0 = __builtin_amdgcn_mfma_f32_32x32x16_bf16(pa, v0, OB0, 0, 0, 0);
                OB1 = __builtin_amdgcn_mfma_f32_32x32x16_bf16(pa, v1, OB1, 0, 0, 0);
            }
        }
    }

    lsumA += __shfl_xor(lsumA, 32);
    lsumB += __shfl_xor(lsumB, 32);
    lsum_s[w][lq] = lsumA;
    lsum_s[w][32 + lq] = lsumB;
    int n = nh >> 3, h = nh & 7;
    #pragma unroll
    for (int rq = 0; rq < 4; rq++) {
        float4 lvA = *(const float4*)&lsum_s[w][rq*8 + hi*4];
        float4 lvB = *(const float4*)&lsum_s[w][32 + rq*8 + hi*4];
        float invA[4] = {1.f/lvA.x, 1.f/lvA.y, 1.f/lvA.z, 1.f/lvA.w};
        float invB[4] = {1.f/lvB.x, 1.f/lvB.y, 1.f/lvB.z, 1.f/lvB.w};
        #pragma unroll
        for (int i = 0; i < 4; i++) {
            int sA = q0 + rq*8 + hi*4 + i;
            size_t rowA = ((size_t)(n*1024 + sA))*512 + h*64;
            ao[rowA + lq]      = (unsigned short)f2bf_rn(OA0[rq*4+i] * invA[i]);
            ao[rowA + 32 + lq] = (unsigned short)f2bf_rn(OA1[rq*4+i] * invA[i]);
            int sB = sA + 32;
            size_t rowB = ((size_t)(n*1024 + sB))*512 + h*64;
            ao[rowB + lq]      = (unsigned short)f2bf_rn(OB0[rq*4+i] * invB[i]);
            ao[rowB + 32 + lq] = (unsigned short)f2bf_rn(OB1[rq*4+i] * invB[i]);
        }
    }
}

// ---------------- out GEMM: D[s][d] = sum_c aoT[s][c]*WoT[d][c]; +bias+x ----------------
__global__ __launch_bounds__(256) void out_kernel(
        const unsigned short* __restrict__ aoT, const unsigned short* __restrict__ WoT,
        const float* __restrict__ bout, const float* __restrict__ x,
        float* __restrict__ out) {
    int s0 = blockIdx.x * 128, d0b = blockIdx.y * 128, n = blockIdx.z;
    __shared__ unsigned short At[4096];
    __shared__ unsigned short Bt[4096];
    int tid = threadIdx.x;
    int lane = tid & 63, w = tid >> 6;
    int quad = lane >> 4, tx = lane & 15;
    int moff = (w & 1) * 64, noff = (w >> 1) * 64;

    const unsigned short* Arow = aoT + ((size_t)n * 1024 + s0) * 512;
    const unsigned short* Brow = WoT + (size_t)d0b * 512;

    f32x4v acc[4][4];
    #pragma unroll
    for (int i = 0; i < 4; i++)
        #pragma unroll
        for (int j = 0; j < 4; j++)
            #pragma unroll
            for (int e = 0; e < 4; e++) acc[i][j][e] = 0.f;

    int f1 = tid, f2 = tid + 256;
    int m1 = f1 >> 2, kb1 = ((f1 & 3) - (f1 >> 3)) & 3;
    int m2 = f2 >> 2, kb2 = ((f2 & 3) - (f2 >> 3)) & 3;

    for (int k0 = 0; k0 < 512; k0 += 32) {
        __syncthreads();
        GLD_LDS16(Arow + (size_t)m1*512 + k0 + kb1*8, At + f1*8);
        GLD_LDS16(Arow + (size_t)m2*512 + k0 + kb2*8, At + f2*8);
        GLD_LDS16(Brow + (size_t)m1*512 + k0 + kb1*8, Bt + f1*8);
        GLD_LDS16(Brow + (size_t)m2*512 + k0 + kb2*8, Bt + f2*8);
        __syncthreads();
        bf16x8 af[4], bfr[4];
        #pragma unroll
        for (int mt = 0; mt < 4; mt++) {
            int m = moff + mt*16 + tx;
            int ch = m*4 + ((quad + (m >> 1)) & 3);
            af[mt] = *(const bf16x8*)(At + ch*8);
        }
        #pragma unroll
        for (int nt = 0; nt < 4; nt++) {
            int m = noff + nt*16 + tx;
            int ch = m*4 + ((quad + (m >> 1)) & 3);
            bfr[nt] = *(const bf16x8*)(Bt + ch*8);
        }
        #pragma unroll
        for (int mt = 0; mt < 4; mt++)
            #pragma unroll
            for (int nt = 0; nt < 4; nt++)
                acc[mt][nt] = __builtin_amdgcn_mfma_f32_16x16x32_bf16(
                    af[mt], bfr[nt], acc[mt][nt], 0, 0, 0);
    }

    #pragma unroll
    for (int mt = 0; mt < 4; mt++) {
        int sQ = s0 + moff + mt*16 + quad*4;
        #pragma unroll
        for (int nt = 0; nt < 4; nt++) {
            int d = d0b + noff + nt*16 + tx;
            float bo = bout[d];
            size_t base = ((size_t)n*512 + d)*1024 + sQ;
            float4 xv = *(const float4*)(x + base);
            f32x4v a = acc[mt][nt];
            float4 o = make_float4(a[0]+bo+xv.x, a[1]+bo+xv.y, a[2]+bo+xv.z, a[3]+bo+xv.w);
            *(float4*)(out + base) = o;
        }
    }
}

extern "C" void kernel_launch(void* const* d_in, const int* in_sizes, int n_in,
                              void* d_out, int out_size, void* d_ws, size_t ws_size,
                              hipStream_t stream) {
    const float* x    = (const float*)d_in[0];
    const float* gns  = (const float*)d_in[1];
    const float* gnb  = (const float*)d_in[2];
    const float* wqkv = (const float*)d_in[3];
    const float* bqkv = (const float*)d_in[4];
    const float* wout = (const float*)d_in[5];
    const float* bout = (const float*)d_in[6];
    float* out = (float*)d_out;

    char* p = (char*)d_ws;
    size_t off = 0;
    auto carve = [&](size_t bytes) {
        char* r = p + off;
        off = (off + bytes + 255) & ~(size_t)255;
        return r;
    };
    unsigned short* hnT = (unsigned short*)carve((size_t)16*1024*512*2);
    unsigned short* qb2 = (unsigned short*)carve((size_t)128*1024*64*2);
    unsigned short* kb2 = (unsigned short*)carve((size_t)128*1024*64*2);
    unsigned short* vb2 = (unsigned short*)carve((size_t)128*64*1024*2);
    unsigned short* aoT = (unsigned short*)carve((size_t)16*1024*512*2);
    unsigned short* WqT = (unsigned short*)carve((size_t)1536*512*2);
    unsigned short* WoT = (unsigned short*)carve((size_t)512*512*2);

    prep_kernel<<<dim3(1536), 256, 0, stream>>>(x, gns, gnb, hnT, wqkv, wout, WqT, WoT);
    qkv_kernel<<<dim3(8, 12, 16), 256, 0, stream>>>(WqT, hnT, bqkv, qb2, kb2, vb2);
    attn_kernel<<<dim3(512), 256, 0, stream>>>(qb2, kb2, vb2, aoT);
    out_kernel<<<dim3(8, 4, 16), 256, 0, stream>>>(aoT, WoT, bout, x, out);
}